// Round 7
// baseline (2068.348 us; speedup 1.0000x reference)
//
#include <hip/hip_runtime.h>
#include <hip/hip_bf16.h>

#define NT_ 10000
#define B_  128
#define S_  500

typedef _Float16 h2_t __attribute__((ext_vector_type(2)));
typedef unsigned int uint32;

__device__ __forceinline__ uint32 pack2(float a, float b) {
    return __builtin_bit_cast(uint32, __builtin_amdgcn_cvt_pkrtz(a, b));
}
__device__ __forceinline__ float dot2(uint32 w, uint32 h, float acc) {
#if __has_builtin(__builtin_amdgcn_fdot2)
    return __builtin_amdgcn_fdot2(__builtin_bit_cast(h2_t, w),
                                  __builtin_bit_cast(h2_t, h), acc, false);
#else
    h2_t wv = __builtin_bit_cast(h2_t, w), hv = __builtin_bit_cast(h2_t, h);
    acc = fmaf((float)wv[0], (float)hv[0], acc);
    return fmaf((float)wv[1], (float)hv[1], acc);
#endif
}

// ---------------------------------------------------------------------------
// Kernel A: per-topic precompute (blockIdx.y = 0: topicAct, 1: topicGate)
// ---------------------------------------------------------------------------
__global__ __launch_bounds__(128) void prep_topic(
    const float* __restrict__ emb_topic,
    const float* __restrict__ emb_resps,
    const float* __restrict__ W_in,
    const float* __restrict__ W_gate,
    float* __restrict__ topicAct,
    float* __restrict__ topicGate,
    float* __restrict__ respAct)
{
    const int u    = threadIdx.x;
    const int blk  = blockIdx.x;
    const int mode = blockIdx.y;
    __shared__ float e[8][128];

    if (blk == NT_ / 8) {
        if (mode) return;
        e[0][u] = emb_resps[u];
        e[1][u] = emb_resps[128 + u];
        __syncthreads();
        float a0 = 0.f, a1 = 0.f;
        for (int k = 0; k < 128; ++k) {
            float wv = W_in[(128 + k) * 128 + u];
            a0 += e[0][k] * wv;
            a1 += e[1][k] * wv;
        }
        respAct[u]       = a0;
        respAct[128 + u] = a1;
        return;
    }

    const int t0 = blk * 8;
    #pragma unroll
    for (int j = 0; j < 8; ++j) e[j][u] = emb_topic[(t0 + j) * 128 + u];
    __syncthreads();

    const float* __restrict__ W = mode ? (W_gate + 256 * 128) : W_in;
    float acc[8];
    #pragma unroll
    for (int j = 0; j < 8; ++j) acc[j] = 0.f;
    for (int k = 0; k < 128; ++k) {
        float wv = W[k * 128 + u];
        #pragma unroll
        for (int j = 0; j < 8; ++j) acc[j] += e[j][k] * wv;
    }
    float* __restrict__ dst = mode ? topicGate : topicAct;
    #pragma unroll
    for (int j = 0; j < 8; ++j) dst[(t0 + j) * 128 + u] = acc[j];
}

// ---------------------------------------------------------------------------
// Kernel B: per-(topic,resp) streams (blockIdx.y = mat 0..3)
//   streams[(t*2+r)*512 + m*128 + u]: m0: a@W_time[1:129]  m1: a@W_att[1:129]
//                                     m2: a@W_hint[1:129]  m3: a@W_gate[128:256]+topicGate
// ---------------------------------------------------------------------------
__global__ __launch_bounds__(128) void prep_streams(
    const float* __restrict__ topicAct,
    const float* __restrict__ topicGate,
    const float* __restrict__ respAct,
    const float* __restrict__ b_in,
    const float* __restrict__ W_time,
    const float* __restrict__ W_att,
    const float* __restrict__ W_hint,
    const float* __restrict__ W_gate,
    float* __restrict__ streams)
{
    const int u   = threadIdx.x;
    const int t0  = blockIdx.x * 8;
    const int mat = blockIdx.y;
    __shared__ float a_lds[16][128];

    const float bi = b_in[u];
    const float r0 = respAct[u];
    const float r1 = respAct[128 + u];
    #pragma unroll
    for (int j = 0; j < 8; ++j) {
        float ta = topicAct[(t0 + j) * 128 + u];
        a_lds[j * 2 + 0][u] = fmaxf(ta + r0 + bi, 0.f);
        a_lds[j * 2 + 1][u] = fmaxf(ta + r1 + bi, 0.f);
    }
    __syncthreads();

    const float* __restrict__ Wp =
        (mat == 0 ? W_time + 128 : mat == 1 ? W_att + 128 :
         mat == 2 ? W_hint + 128 : W_gate + 128 * 128) + u;

    float acc[16];
    #pragma unroll
    for (int r = 0; r < 16; ++r) acc[r] = 0.f;
    for (int k = 0; k < 128; ++k) {
        float wv = Wp[(size_t)k * 128];
        #pragma unroll
        for (int r = 0; r < 16; ++r) acc[r] += a_lds[r][k] * wv;
    }
    #pragma unroll
    for (int r = 0; r < 16; ++r) {
        float v = acc[r];
        int   t = t0 + (r >> 1);
        if (mat == 3) v += topicGate[t * 128 + u];
        streams[((size_t)t * 2 + (r & 1)) * 512 + mat * 128 + u] = v;
    }
}

// ---------------------------------------------------------------------------
// Kernel C: 500-step recurrence. TWO rows per block: 1024 thr = 2 x 512.
//   half = tid>>9 (row), htid = tid&511, u = htid>>2, mat = htid&3.
// Each SIMD hosts 4 waves (2 per row) - two INDEPENDENT dependency chains
// interleave, covering each other's DS-latency stalls (R5 was 2 waves/SIMD
// = one chain, 70% stall; R6's 4-wave attempt spilled at VGPR=64).
// waves_per_eu(4,4) pins the 128-VGPR budget; live set ~112 (R5-measured).
//   mat0: W_out (sig) + gate k 0:32     mat1: W_time (gt) + gate k 32:64
//   mat2: W_att (ga)  + gate k 64:96    mat3: W_hint (gh) + gate k 96:128
// Per-step data + cap precomputed in LDS. One LDS-only barrier per step.
// ---------------------------------------------------------------------------
__device__ __forceinline__ float sigmoidf_(float x) {
    return 1.f / (1.f + __expf(-x));
}
__device__ __forceinline__ float tanhf_(float x) {
    float e = __expf(2.f * x);
    return 1.f - 2.f / (e + 1.f);
}

#define LDS_BARRIER()                                         \
    do {                                                      \
        asm volatile("s_waitcnt lgkmcnt(0)" ::: "memory");    \
        __builtin_amdgcn_s_barrier();                         \
        asm volatile("" ::: "memory");                        \
    } while (0)

__global__ __launch_bounds__(1024) __attribute__((amdgpu_waves_per_eu(4, 4)))
void recurrent(
    const int*   __restrict__ topics, const int* __restrict__ resps,
    const float* __restrict__ tf_, const float* __restrict__ af_,
    const float* __restrict__ hf_, const int* __restrict__ masks,
    const float* __restrict__ q_matrix, const float* __restrict__ init_h,
    const float* __restrict__ W_out,  const float* __restrict__ b_out,
    const float* __restrict__ W_time, const float* __restrict__ b_time,
    const float* __restrict__ W_att,  const float* __restrict__ b_att,
    const float* __restrict__ W_hint, const float* __restrict__ b_hint,
    const float* __restrict__ W_cap,  const float* __restrict__ b_cap,
    const float* __restrict__ w_lg,
    const float* __restrict__ W_gate, const float* __restrict__ b_gate,
    const float* __restrict__ streams,
    float* __restrict__ out)
{
    const int tid  = threadIdx.x;
    const int half = tid >> 9;       // which row of the pair
    const int htid = tid & 511;
    const int u    = htid >> 2;      // 0..127
    const int mat  = htid & 3;       // role
    const int lane = tid & 63;
    const int hwv  = (tid >> 6) & 7; // wave index within half (0..7)
    const int row  = blockIdx.x * 2 + half;

    __shared__ int    sb_lds[2][S_];           // (topic*2+resp)*512
    __shared__ int    qb_lds[2][S_];           // topic*32
    __shared__ float4 sc_lds[2][S_];           // {tf, af, hf, mask}
    __shared__ float  cap_lds[2][S_];          // precomputed cap
    __shared__ float  w_lds[2][2][32];
    __shared__ __align__(16) uint32 ht_pk[2][2][64];
    __shared__ float  outbuf[2][8][2][128];    // [half][slot][which][u]

    const int base = row * S_;

    // ---- preload per-step data + precompute cap (per half) ----
    {
        const float wcv0 = W_cap[0], wcv1 = W_cap[1], wcv2 = W_cap[2],
                    wcv3 = W_cap[3], wcv4 = W_cap[4], wcv5 = W_cap[5],
                    wcv6 = W_cap[6], wcv7 = W_cap[7], bcv = b_cap[0];
        for (int i = htid; i < S_; i += 512) {
            const int tpc = topics[base + i];
            const int rsp = resps [base + i];
            sb_lds[half][i] = (tpc * 2 + rsp) * 512;
            qb_lds[half][i] = tpc * 32;
            const float tf = tf_[base + i], af = af_[base + i], hf = hf_[base + i];
            sc_lds[half][i] = make_float4(tf, af, hf, masks[base + i] ? 1.f : 0.f);
            const float capin = wcv0*tf + wcv1*af + wcv2*hf + wcv3*(tf*af)
                              + wcv4*(tf*hf) + wcv5*(af*hf) + wcv6*(tf*af*hf)
                              + wcv7 + bcv;
            cap_lds[half][i] = 1.f / (1.f + __expf(-capin));
        }
    }

    // ---- f16-packed weights: own matrix full k=128 + gate k-slice ----
    const float* __restrict__ WpA =
        mat == 0 ? W_out :
        mat == 1 ? W_time + 129 * 128 :
        mat == 2 ? W_att  + 129 * 128 : W_hint + 129 * 128;
    uint32 Wn[64], Wg[16];
    #pragma unroll
    for (int i = 0; i < 64; ++i)
        Wn[i] = pack2(WpA[(2 * i) * 128 + u], WpA[(2 * i + 1) * 128 + u]);
    #pragma unroll
    for (int i = 0; i < 16; ++i)
        Wg[i] = pack2(W_gate[(mat * 32 + 2 * i) * 128 + u],
                      W_gate[(mat * 32 + 2 * i + 1) * 128 + u]);
    #pragma unroll
    for (int i = 0; i < 16; ++i) {
        asm volatile("" : "+v"(Wn[4*i]), "+v"(Wn[4*i+1]), "+v"(Wn[4*i+2]),
                          "+v"(Wn[4*i+3]), "+v"(Wg[i]));
    }

    // H[m][u] for m = mat*8 .. mat*8+7
    float H[8];
    #pragma unroll
    for (int j = 0; j < 8; ++j) H[j] = init_h[(mat * 8 + j) * 128 + u];

    // per-lane role constants
    const float cst_b  = (mat == 0 ? b_out : mat == 1 ? b_time :
                          mat == 2 ? b_att : b_hint)[u];
    const float cst_w0 = mat == 1 ? W_time[u] : mat == 2 ? W_att[u] :
                         mat == 3 ? W_hint[u] : 0.f;
    const float wl_own = mat == 1 ? w_lg[0] : mat == 2 ? w_lg[1] :
                         mat == 3 ? w_lg[2] : 0.f;
    const float bg = b_gate[u];
    const int   svofs = (mat == 0 ? 384 : (mat - 1) * 128) + u;

    float* out_imp = out + B_ * (S_ - 1);

    __syncthreads();   // preload visible

    // ---- prime 2-deep pipelines (per half) ----
    float sv_cur = streams[sb_lds[half][0] + svofs];
    float sv_nxt = streams[sb_lds[half][1] + svofs];
    float qv_cur = 0.f;
    if (htid < 32) {
        w_lds[half][0][htid] = q_matrix[qb_lds[half][0] + htid];
        qv_cur               = q_matrix[qb_lds[half][1] + htid];
    }
    __syncthreads();
    float4 wA = *(const float4*)&w_lds[half][0][mat * 8];
    float4 wB = *(const float4*)&w_lds[half][0][mat * 8 + 4];

    #pragma unroll 1
    for (int s = 0; s < S_; ++s) {
        const int buf = s & 1;

        // per-step scalars (broadcast LDS) + prefetch issue for s+2
        const float4 sc  = sc_lds[half][s];
        const float  cap = cap_lds[half][s];
        const float tf = sc.x, af = sc.y, hf = sc.z, msk = sc.w;
        const int s2 = (s + 2 < S_) ? s + 2 : S_ - 1;
        const float sv_new = streams[sb_lds[half][s2] + svofs];
        float qv_new = 0.f;
        if (htid < 32) qv_new = q_matrix[qb_lds[half][s2] + htid];
        const float sv3b = __shfl(sv_cur, lane & ~3);   // gate stream (mat0 lane)

        // ---- h_tilde partial + reduce over the 4 role lanes ----
        float hp = wA.x * H[0] + wA.y * H[1] + wA.z * H[2] + wA.w * H[3]
                 + wB.x * H[4] + wB.y * H[5] + wB.z * H[6] + wB.w * H[7];
        hp += __shfl_xor(hp, 1);
        hp += __shfl_xor(hp, 2);
        const float hp2 = __shfl_down(hp, 4);           // ht of unit u+1
        if (mat == 0 && !(u & 1)) ht_pk[half][buf][u >> 1] = pack2(hp, hp2);
        if (htid < 32) w_lds[half][buf ^ 1][htid] = qv_cur;  // w row for s+1
        LDS_BARRIER();

        // ---- deferred output flush: every 4 steps, 8 waves per half ----
        if ((s & 3) == 0 && s) {
            const int st = (s - 4) + (hwv >> 1);
            const int which = hwv & 1;
            const float2 p = *(const float2*)&outbuf[half][st & 7][which][2 * lane];
            float v = p.x + p.y;
            #pragma unroll
            for (int o = 1; o < 64; o <<= 1) v += __shfl_xor(v, o);
            if (lane == 0) {
                v *= (1.f / 128.f);
                if (which == 0) { if (st >= 1) out[row * (S_ - 1) + st - 1] = v; }
                else            out_imp[row * S_ + st] = v;
            }
        }

        const float4 wAn = *(const float4*)&w_lds[half][buf ^ 1][mat * 8];
        const float4 wBn = *(const float4*)&w_lds[half][buf ^ 1][mat * 8 + 4];

        // ---- own-matrix dot: full k=128 in-lane, no reduce ----
        const uint4* htb = (const uint4*)&ht_pk[half][buf][0];
        float x0 = 0, x1 = 0, x2 = 0, x3 = 0;
        #pragma unroll
        for (int c = 0; c < 16; ++c) {
            const uint4 h4 = htb[c];
            x0 = dot2(Wn[c*4+0], h4.x, x0);
            x1 = dot2(Wn[c*4+1], h4.y, x1);
            x2 = dot2(Wn[c*4+2], h4.z, x2);
            x3 = dot2(Wn[c*4+3], h4.w, x3);
        }
        const float z = (x0 + x1) + (x2 + x3);

        // ---- gate dot: k-slice of 32, reduce over 4 lanes ----
        const uint4* htg = htb + mat * 4;
        float g0 = 0, g1 = 0, g2 = 0, g3 = 0;
        #pragma unroll
        for (int c = 0; c < 4; ++c) {
            const uint4 h4 = htg[c];
            g0 = dot2(Wg[c*4+0], h4.x, g0);
            g1 = dot2(Wg[c*4+1], h4.y, g1);
            g2 = dot2(Wg[c*4+2], h4.z, g2);
            g3 = dot2(Wg[c*4+3], h4.w, g3);
        }
        float z4 = (g0 + g1) + (g2 + g3);
        z4 += __shfl_xor(z4, 1);
        z4 += __shfl_xor(z4, 2);

        // ---- epilogue: roles in parallel lanes ----
        const float fac = mat == 1 ? tf : mat == 2 ? af : mat == 3 ? hf : 0.f;
        const float arg = z + (mat ? sv_cur : 0.f) + fac * cst_w0 + cst_b;
        const float g   = tanhf_(arg) * fac;
        float gs = wl_own * g;
        gs += __shfl_xor(gs, 1);
        gs += __shfl_xor(gs, 2);
        const float lg    = cap * fmaxf(gs, 0.f);
        const float gamma = sigmoidf_(z4 + sv3b + bg);

        const float gme = 1.f + msk * (gamma - 1.f);
        const float lge = msk * lg;
        H[0] = fmaf(gme, H[0], wA.x * lge); H[1] = fmaf(gme, H[1], wA.y * lge);
        H[2] = fmaf(gme, H[2], wA.z * lge); H[3] = fmaf(gme, H[3], wA.w * lge);
        H[4] = fmaf(gme, H[4], wB.x * lge); H[5] = fmaf(gme, H[5], wB.y * lge);
        H[6] = fmaf(gme, H[6], wB.z * lge); H[7] = fmaf(gme, H[7], wB.w * lge);

        if (mat == 0) {
            const float sig = sigmoidf_(arg);           // arg = z0 + bo here
            outbuf[half][s & 7][0][u] = msk * sig;
            outbuf[half][s & 7][1][u] = lge;
        }

        // rotate pipelines
        wA = wAn; wB = wBn;
        sv_cur = sv_nxt; sv_nxt = sv_new; qv_cur = qv_new;
    }

    // ---- final flush: steps 496..499 ----
    __syncthreads();
    {
        const int st = 496 + (hwv >> 1);
        const int which = hwv & 1;
        const float2 p = *(const float2*)&outbuf[half][st & 7][which][2 * lane];
        float v = p.x + p.y;
        #pragma unroll
        for (int o = 1; o < 64; o <<= 1) v += __shfl_xor(v, o);
        if (lane == 0) {
            v *= (1.f / 128.f);
            if (which == 0) out[row * (S_ - 1) + st - 1] = v;
            else            out_imp[row * S_ + st] = v;
        }
    }
}

// ---------------------------------------------------------------------------
extern "C" void kernel_launch(void* const* d_in, const int* in_sizes, int n_in,
                              void* d_out, int out_size, void* d_ws, size_t ws_size,
                              hipStream_t stream)
{
    (void)in_sizes; (void)n_in; (void)out_size; (void)ws_size;

    const int*   topics    = (const int*)  d_in[0];
    const int*   resps     = (const int*)  d_in[1];
    const float* tf        = (const float*)d_in[2];
    const float* af        = (const float*)d_in[3];
    const float* hf        = (const float*)d_in[4];
    const int*   masks     = (const int*)  d_in[5];
    /* d_in[6] = training (ignored) */
    const float* emb_topic = (const float*)d_in[7];
    const float* emb_resps = (const float*)d_in[8];
    const float* q_matrix  = (const float*)d_in[9];
    const float* W_in      = (const float*)d_in[10];
    const float* b_in      = (const float*)d_in[11];
    const float* init_h    = (const float*)d_in[12];
    const float* W_out     = (const float*)d_in[13];
    const float* b_out     = (const float*)d_in[14];
    const float* W_time    = (const float*)d_in[15];
    const float* b_time    = (const float*)d_in[16];
    const float* W_att     = (const float*)d_in[17];
    const float* b_att     = (const float*)d_in[18];
    const float* W_hint    = (const float*)d_in[19];
    const float* b_hint    = (const float*)d_in[20];
    const float* W_cap     = (const float*)d_in[21];
    const float* b_cap     = (const float*)d_in[22];
    const float* w_lg      = (const float*)d_in[23];
    const float* W_gate    = (const float*)d_in[24];
    const float* b_gate    = (const float*)d_in[25];

    float* ws        = (float*)d_ws;
    float* topicAct  = ws;                         // 10000*128
    float* topicGate = topicAct + NT_ * 128;       // 10000*128
    float* respAct   = topicGate + NT_ * 128;      // 256
    float* streams   = respAct + 256;              // 10000*2*512

    prep_topic  <<<dim3(NT_ / 8 + 1, 2), 128, 0, stream>>>(
        emb_topic, emb_resps, W_in, W_gate, topicAct, topicGate, respAct);
    prep_streams<<<dim3(NT_ / 8, 4),     128, 0, stream>>>(
        topicAct, topicGate, respAct, b_in,
        W_time, W_att, W_hint, W_gate, streams);
    recurrent   <<<B_ / 2, 1024, 0, stream>>>(topics, resps, tf, af, hf, masks,
                                              q_matrix, init_h,
                                              W_out, b_out, W_time, b_time,
                                              W_att, b_att, W_hint, b_hint,
                                              W_cap, b_cap, w_lg, W_gate, b_gate,
                                              streams, (float*)d_out);
}

// Round 8
// 664.669 us; speedup vs baseline: 3.1118x; 3.1118x over previous
//
#include <hip/hip_runtime.h>
#include <hip/hip_bf16.h>

#define NT_ 10000
#define B_  128
#define S_  500

typedef _Float16 h2_t __attribute__((ext_vector_type(2)));
typedef unsigned int uint32;

__device__ __forceinline__ uint32 pack2(float a, float b) {
    return __builtin_bit_cast(uint32, __builtin_amdgcn_cvt_pkrtz(a, b));
}
__device__ __forceinline__ float dot2(uint32 w, uint32 h, float acc) {
#if __has_builtin(__builtin_amdgcn_fdot2)
    return __builtin_amdgcn_fdot2(__builtin_bit_cast(h2_t, w),
                                  __builtin_bit_cast(h2_t, h), acc, false);
#else
    h2_t wv = __builtin_bit_cast(h2_t, w), hv = __builtin_bit_cast(h2_t, h);
    acc = fmaf((float)wv[0], (float)hv[0], acc);
    return fmaf((float)wv[1], (float)hv[1], acc);
#endif
}
// quad_perm DPP add-reduce stage: x += x[lane ^ k] for k=1 (0xB1), k=2 (0x4E).
// VALU-pipe cross-lane: no DS-pipe occupancy (the whole point of round 8).
__device__ __forceinline__ float qstep(float x, const int ctrl) {
    int p;
    if (ctrl == 0xB1)
        p = __builtin_amdgcn_update_dpp(0, __builtin_bit_cast(int, x), 0xB1, 0xF, 0xF, true);
    else
        p = __builtin_amdgcn_update_dpp(0, __builtin_bit_cast(int, x), 0x4E, 0xF, 0xF, true);
    return x + __builtin_bit_cast(float, p);
}
#define QUAD_SUM(x) do { x = qstep(x, 0xB1); x = qstep(x, 0x4E); } while (0)

// ---------------------------------------------------------------------------
// Kernel A: per-topic precompute (blockIdx.y = 0: topicAct, 1: topicGate)
// ---------------------------------------------------------------------------
__global__ __launch_bounds__(128) void prep_topic(
    const float* __restrict__ emb_topic,
    const float* __restrict__ emb_resps,
    const float* __restrict__ W_in,
    const float* __restrict__ W_gate,
    float* __restrict__ topicAct,
    float* __restrict__ topicGate,
    float* __restrict__ respAct)
{
    const int u    = threadIdx.x;
    const int blk  = blockIdx.x;
    const int mode = blockIdx.y;
    __shared__ float e[8][128];

    if (blk == NT_ / 8) {
        if (mode) return;
        e[0][u] = emb_resps[u];
        e[1][u] = emb_resps[128 + u];
        __syncthreads();
        float a0 = 0.f, a1 = 0.f;
        for (int k = 0; k < 128; ++k) {
            float wv = W_in[(128 + k) * 128 + u];
            a0 += e[0][k] * wv;
            a1 += e[1][k] * wv;
        }
        respAct[u]       = a0;
        respAct[128 + u] = a1;
        return;
    }

    const int t0 = blk * 8;
    #pragma unroll
    for (int j = 0; j < 8; ++j) e[j][u] = emb_topic[(t0 + j) * 128 + u];
    __syncthreads();

    const float* __restrict__ W = mode ? (W_gate + 256 * 128) : W_in;
    float acc[8];
    #pragma unroll
    for (int j = 0; j < 8; ++j) acc[j] = 0.f;
    for (int k = 0; k < 128; ++k) {
        float wv = W[k * 128 + u];
        #pragma unroll
        for (int j = 0; j < 8; ++j) acc[j] += e[j][k] * wv;
    }
    float* __restrict__ dst = mode ? topicGate : topicAct;
    #pragma unroll
    for (int j = 0; j < 8; ++j) dst[(t0 + j) * 128 + u] = acc[j];
}

// ---------------------------------------------------------------------------
// Kernel B: per-(topic,resp) streams (blockIdx.y = mat 0..3)
//   streams[(t*2+r)*512 + m*128 + u]: m0: a@W_time[1:129]  m1: a@W_att[1:129]
//                                     m2: a@W_hint[1:129]  m3: a@W_gate[128:256]+topicGate
// ---------------------------------------------------------------------------
__global__ __launch_bounds__(128) void prep_streams(
    const float* __restrict__ topicAct,
    const float* __restrict__ topicGate,
    const float* __restrict__ respAct,
    const float* __restrict__ b_in,
    const float* __restrict__ W_time,
    const float* __restrict__ W_att,
    const float* __restrict__ W_hint,
    const float* __restrict__ W_gate,
    float* __restrict__ streams)
{
    const int u   = threadIdx.x;
    const int t0  = blockIdx.x * 8;
    const int mat = blockIdx.y;
    __shared__ float a_lds[16][128];

    const float bi = b_in[u];
    const float r0 = respAct[u];
    const float r1 = respAct[128 + u];
    #pragma unroll
    for (int j = 0; j < 8; ++j) {
        float ta = topicAct[(t0 + j) * 128 + u];
        a_lds[j * 2 + 0][u] = fmaxf(ta + r0 + bi, 0.f);
        a_lds[j * 2 + 1][u] = fmaxf(ta + r1 + bi, 0.f);
    }
    __syncthreads();

    const float* __restrict__ Wp =
        (mat == 0 ? W_time + 128 : mat == 1 ? W_att + 128 :
         mat == 2 ? W_hint + 128 : W_gate + 128 * 128) + u;

    float acc[16];
    #pragma unroll
    for (int r = 0; r < 16; ++r) acc[r] = 0.f;
    for (int k = 0; k < 128; ++k) {
        float wv = Wp[(size_t)k * 128];
        #pragma unroll
        for (int r = 0; r < 16; ++r) acc[r] += a_lds[r][k] * wv;
    }
    #pragma unroll
    for (int r = 0; r < 16; ++r) {
        float v = acc[r];
        int   t = t0 + (r >> 1);
        if (mat == 3) v += topicGate[t * 128 + u];
        streams[((size_t)t * 2 + (r & 1)) * 512 + mat * 128 + u] = v;
    }
}

// ---------------------------------------------------------------------------
// Kernel C: 500-step recurrence. 1 block/row, 512 thr = 128 u x 4 k-quads.
// R5 was LDS-PIPE-bound (~2350 DS-cyc/CU-step: every lane read the full
// 256B ht + 8 ds_permute shfls). This version:
//  - lane (u,q) reads ONLY its k-quad of ht: 4 x b128 (4x less)
//  - ALL quad reduces via DPP quad_perm on the VALU pipe (zero DS)
//  - sv stream values folded into z partials pre-reduce (no sv shuffle)
//  - ht written as ds_write_b16 by q0 lanes (no pack shuffle)
//  - epilogue fully redundant across the 4 q-lanes (no broadcasts)
// ---------------------------------------------------------------------------
__device__ __forceinline__ float sigmoidf_(float x) {
    return 1.f / (1.f + __expf(-x));
}
__device__ __forceinline__ float tanhf_(float x) {
    float e = __expf(2.f * x);
    return 1.f - 2.f / (e + 1.f);
}

#define LDS_BARRIER()                                         \
    do {                                                      \
        asm volatile("s_waitcnt lgkmcnt(0)" ::: "memory");    \
        __builtin_amdgcn_s_barrier();                         \
        asm volatile("" ::: "memory");                        \
    } while (0)

__global__ __launch_bounds__(512) __attribute__((amdgpu_waves_per_eu(2, 2)))
void recurrent(
    const int*   __restrict__ topics, const int* __restrict__ resps,
    const float* __restrict__ tf_, const float* __restrict__ af_,
    const float* __restrict__ hf_, const int* __restrict__ masks,
    const float* __restrict__ q_matrix, const float* __restrict__ init_h,
    const float* __restrict__ W_out,  const float* __restrict__ b_out,
    const float* __restrict__ W_time, const float* __restrict__ b_time,
    const float* __restrict__ W_att,  const float* __restrict__ b_att,
    const float* __restrict__ W_hint, const float* __restrict__ b_hint,
    const float* __restrict__ W_cap,  const float* __restrict__ b_cap,
    const float* __restrict__ w_lg,
    const float* __restrict__ W_gate, const float* __restrict__ b_gate,
    const float* __restrict__ streams,
    float* __restrict__ out)
{
    const int tid  = threadIdx.x;
    const int u    = tid >> 2;      // 0..127
    const int q    = tid & 3;       // k-quad
    const int lane = tid & 63;
    const int wv   = tid >> 6;      // wave 0..7
    const int b    = blockIdx.x;

    __shared__ int    sb_lds[S_];             // (topic*2+resp)*512
    __shared__ int    qb_lds[S_];             // topic*32
    __shared__ float4 sc_lds[S_];             // {tf, af, hf, capm(sign=mask)}
    __shared__ float  w_lds[2][32];
    __shared__ __align__(16) _Float16 ht16[2][176];  // quads at q*40 (bank-spread)
    __shared__ float  outbuf[8][2][128];      // [slot][which][u]

    const int base = b * S_;

    // ---- preload per-step data; fold cap+mask into sc.w ----
    {
        const float wcv0 = W_cap[0], wcv1 = W_cap[1], wcv2 = W_cap[2],
                    wcv3 = W_cap[3], wcv4 = W_cap[4], wcv5 = W_cap[5],
                    wcv6 = W_cap[6], wcv7 = W_cap[7], bcv = b_cap[0];
        for (int i = tid; i < S_; i += 512) {
            const int tpc = topics[base + i];
            const int rsp = resps [base + i];
            sb_lds[i] = (tpc * 2 + rsp) * 512;
            qb_lds[i] = tpc * 32;
            const float tf = tf_[base + i], af = af_[base + i], hf = hf_[base + i];
            const float capin = wcv0*tf + wcv1*af + wcv2*hf + wcv3*(tf*af)
                              + wcv4*(tf*hf) + wcv5*(af*hf) + wcv6*(tf*af*hf)
                              + wcv7 + bcv;
            const float cap = 1.f / (1.f + __expf(-capin));
            sc_lds[i] = make_float4(tf, af, hf, masks[base + i] ? cap : -cap);
        }
    }

    // ---- f16-packed weights: ALL 5 mats for this lane's k-quad (80 u32) ----
    uint32 Wo[16], Wt[16], Wa[16], Wh[16], Wg[16];
    const int kb = q * 32;
    #pragma unroll
    for (int i = 0; i < 16; ++i) {
        const int k0 = kb + 2 * i, k1 = k0 + 1;
        Wo[i] = pack2(W_out [k0 * 128 + u],         W_out [k1 * 128 + u]);
        Wt[i] = pack2(W_time[(129 + k0) * 128 + u], W_time[(129 + k1) * 128 + u]);
        Wa[i] = pack2(W_att [(129 + k0) * 128 + u], W_att [(129 + k1) * 128 + u]);
        Wh[i] = pack2(W_hint[(129 + k0) * 128 + u], W_hint[(129 + k1) * 128 + u]);
        Wg[i] = pack2(W_gate[k0 * 128 + u],         W_gate[k1 * 128 + u]);
    }
    #pragma unroll
    for (int i = 0; i < 16; ++i) {
        asm volatile("" : "+v"(Wo[i]), "+v"(Wt[i]), "+v"(Wa[i]),
                          "+v"(Wh[i]), "+v"(Wg[i]));
    }

    // H[m][u] for m = q*8 .. q*8+7
    float H[8];
    #pragma unroll
    for (int j = 0; j < 8; ++j) H[j] = init_h[(q * 8 + j) * 128 + u];

    // per-u constants (epilogue redundant over q -> every lane needs all)
    const float bo = b_out[u], bt = b_time[u], ba = b_att[u], bh = b_hint[u];
    const float bg = b_gate[u];
    const float wt0 = W_time[u], wa0 = W_att[u], wh0 = W_hint[u];
    const float wl0 = w_lg[0], wl1 = w_lg[1], wl2 = w_lg[2];
    // sv gather role: lane q gathers stream of mat q+1 (time,att,hint,gate)
    const int   svofs = q * 128 + u;
    const float selt = (q == 0) ? 1.f : 0.f;
    const float sela = (q == 1) ? 1.f : 0.f;
    const float selh = (q == 2) ? 1.f : 0.f;
    const float selg = (q == 3) ? 1.f : 0.f;

    float* out_imp = out + B_ * (S_ - 1);

    __syncthreads();   // preload visible

    // ---- prime pipelines ----
    float sv_cur = streams[sb_lds[0] + svofs];
    float sv_nxt = streams[sb_lds[1] + svofs];
    float qv_cur = 0.f;
    if (tid < 32) {
        w_lds[0][tid] = q_matrix[qb_lds[0] + tid];
        qv_cur        = q_matrix[qb_lds[1] + tid];
    }
    __syncthreads();
    float4 wA = *(const float4*)&w_lds[0][q * 8];
    float4 wB = *(const float4*)&w_lds[0][q * 8 + 4];

    #pragma unroll 1
    for (int s = 0; s < S_; ++s) {
        const int buf = s & 1;

        // per-step scalars + prefetch issue for s+2
        const float4 sc = sc_lds[s];
        const float tf = sc.x, af = sc.y, hf = sc.z;
        const float cap = fabsf(sc.w);
        const float msk = sc.w > 0.f ? 1.f : 0.f;
        const int s2 = (s + 2 < S_) ? s + 2 : S_ - 1;
        const float sv_new = streams[sb_lds[s2] + svofs];
        float qv_new = 0.f;
        if (tid < 32) qv_new = q_matrix[qb_lds[s2] + tid];

        // ---- h_tilde: 8-FMA partial + DPP quad reduce (VALU-only) ----
        float hp = wA.x * H[0] + wA.y * H[1] + wA.z * H[2] + wA.w * H[3]
                 + wB.x * H[4] + wB.y * H[5] + wB.z * H[6] + wB.w * H[7];
        QUAD_SUM(hp);
        if (q == 0) ht16[buf][(u >> 5) * 40 + (u & 31)] = (_Float16)hp;
        if (tid < 32) w_lds[buf ^ 1][tid] = qv_cur;    // w row for s+1
        LDS_BARRIER();

        // ---- deferred output flush: every 4 steps, 8 waves ----
        if ((s & 3) == 0 && s) {
            const int st = (s - 4) + (wv >> 1);
            const int which = wv & 1;
            const float2 p = *(const float2*)&outbuf[st & 7][which][2 * lane];
            float v = p.x + p.y;
            #pragma unroll
            for (int o = 1; o < 64; o <<= 1) v += __shfl_xor(v, o);
            if (lane == 0) {
                v *= (1.f / 128.f);
                if (which == 0) { if (st >= 1) out[b * (S_ - 1) + st - 1] = v; }
                else            out_imp[b * S_ + st] = v;
            }
        }

        const float4 wAn = *(const float4*)&w_lds[buf ^ 1][q * 8];
        const float4 wBn = *(const float4*)&w_lds[buf ^ 1][q * 8 + 4];

        // ---- 5 dots over OWN k-quad only: 4 x ds_read_b128 + 80 dot2 ----
        const _Float16* htq = &ht16[buf][q * 40];
        float zo = 0, zt = 0, za = 0, zh = 0, zg = 0;
        #pragma unroll
        for (int c = 0; c < 4; ++c) {
            const uint4 h4 = *(const uint4*)(htq + c * 8);
            zo = dot2(Wo[c*4+0], h4.x, zo); zo = dot2(Wo[c*4+1], h4.y, zo);
            zo = dot2(Wo[c*4+2], h4.z, zo); zo = dot2(Wo[c*4+3], h4.w, zo);
            zt = dot2(Wt[c*4+0], h4.x, zt); zt = dot2(Wt[c*4+1], h4.y, zt);
            zt = dot2(Wt[c*4+2], h4.z, zt); zt = dot2(Wt[c*4+3], h4.w, zt);
            za = dot2(Wa[c*4+0], h4.x, za); za = dot2(Wa[c*4+1], h4.y, za);
            za = dot2(Wa[c*4+2], h4.z, za); za = dot2(Wa[c*4+3], h4.w, za);
            zh = dot2(Wh[c*4+0], h4.x, zh); zh = dot2(Wh[c*4+1], h4.y, zh);
            zh = dot2(Wh[c*4+2], h4.z, zh); zh = dot2(Wh[c*4+3], h4.w, zh);
            zg = dot2(Wg[c*4+0], h4.x, zg); zg = dot2(Wg[c*4+1], h4.y, zg);
            zg = dot2(Wg[c*4+2], h4.z, zg); zg = dot2(Wg[c*4+3], h4.w, zg);
        }
        // fold this lane's gathered stream value into the matching partial
        zt = fmaf(selt, sv_cur, zt);
        za = fmaf(sela, sv_cur, za);
        zh = fmaf(selh, sv_cur, zh);
        zg = fmaf(selg, sv_cur, zg);
        // DPP quad reduces (VALU pipe) -> all 4 lanes hold full z's
        QUAD_SUM(zo); QUAD_SUM(zt); QUAD_SUM(za); QUAD_SUM(zh); QUAD_SUM(zg);

        // ---- epilogue (redundant on the 4 q-lanes of each u) ----
        const float sig   = sigmoidf_(zo + bo);
        const float gt    = tanhf_(zt + tf * wt0 + bt) * tf;
        const float ga    = tanhf_(za + af * wa0 + ba) * af;
        const float gh    = tanhf_(zh + hf * wh0 + bh) * hf;
        const float gamma = sigmoidf_(zg + bg);
        const float lg    = cap * fmaxf(fmaf(wl0, gt, fmaf(wl1, ga, wl2 * gh)), 0.f);

        const float gme = 1.f + msk * (gamma - 1.f);
        const float lge = msk * lg;
        H[0] = fmaf(gme, H[0], wA.x * lge); H[1] = fmaf(gme, H[1], wA.y * lge);
        H[2] = fmaf(gme, H[2], wA.z * lge); H[3] = fmaf(gme, H[3], wA.w * lge);
        H[4] = fmaf(gme, H[4], wB.x * lge); H[5] = fmaf(gme, H[5], wB.y * lge);
        H[6] = fmaf(gme, H[6], wB.z * lge); H[7] = fmaf(gme, H[7], wB.w * lge);

        if (q == 0) {
            outbuf[s & 7][0][u] = msk * sig;
            outbuf[s & 7][1][u] = lge;
        }

        // rotate pipelines
        wA = wAn; wB = wBn;
        sv_cur = sv_nxt; sv_nxt = sv_new; qv_cur = qv_new;
    }

    // ---- final flush: steps 496..499 ----
    __syncthreads();
    {
        const int st = 496 + (wv >> 1);
        const int which = wv & 1;
        const float2 p = *(const float2*)&outbuf[st & 7][which][2 * lane];
        float v = p.x + p.y;
        #pragma unroll
        for (int o = 1; o < 64; o <<= 1) v += __shfl_xor(v, o);
        if (lane == 0) {
            v *= (1.f / 128.f);
            if (which == 0) out[b * (S_ - 1) + st - 1] = v;
            else            out_imp[b * S_ + st] = v;
        }
    }
}

// ---------------------------------------------------------------------------
extern "C" void kernel_launch(void* const* d_in, const int* in_sizes, int n_in,
                              void* d_out, int out_size, void* d_ws, size_t ws_size,
                              hipStream_t stream)
{
    (void)in_sizes; (void)n_in; (void)out_size; (void)ws_size;

    const int*   topics    = (const int*)  d_in[0];
    const int*   resps     = (const int*)  d_in[1];
    const float* tf        = (const float*)d_in[2];
    const float* af        = (const float*)d_in[3];
    const float* hf        = (const float*)d_in[4];
    const int*   masks     = (const int*)  d_in[5];
    /* d_in[6] = training (ignored) */
    const float* emb_topic = (const float*)d_in[7];
    const float* emb_resps = (const float*)d_in[8];
    const float* q_matrix  = (const float*)d_in[9];
    const float* W_in      = (const float*)d_in[10];
    const float* b_in      = (const float*)d_in[11];
    const float* init_h    = (const float*)d_in[12];
    const float* W_out     = (const float*)d_in[13];
    const float* b_out     = (const float*)d_in[14];
    const float* W_time    = (const float*)d_in[15];
    const float* b_time    = (const float*)d_in[16];
    const float* W_att     = (const float*)d_in[17];
    const float* b_att     = (const float*)d_in[18];
    const float* W_hint    = (const float*)d_in[19];
    const float* b_hint    = (const float*)d_in[20];
    const float* W_cap     = (const float*)d_in[21];
    const float* b_cap     = (const float*)d_in[22];
    const float* w_lg      = (const float*)d_in[23];
    const float* W_gate    = (const float*)d_in[24];
    const float* b_gate    = (const float*)d_in[25];

    float* ws        = (float*)d_ws;
    float* topicAct  = ws;                         // 10000*128
    float* topicGate = topicAct + NT_ * 128;       // 10000*128
    float* respAct   = topicGate + NT_ * 128;      // 256
    float* streams   = respAct + 256;              // 10000*2*512

    prep_topic  <<<dim3(NT_ / 8 + 1, 2), 128, 0, stream>>>(
        emb_topic, emb_resps, W_in, W_gate, topicAct, topicGate, respAct);
    prep_streams<<<dim3(NT_ / 8, 4),     128, 0, stream>>>(
        topicAct, topicGate, respAct, b_in,
        W_time, W_att, W_hint, W_gate, streams);
    recurrent   <<<B_, 512, 0, stream>>>(topics, resps, tf, af, hf, masks,
                                         q_matrix, init_h,
                                         W_out, b_out, W_time, b_time,
                                         W_att, b_att, W_hint, b_hint,
                                         W_cap, b_cap, w_lg, W_gate, b_gate,
                                         streams, (float*)d_out);
}

// Round 9
// 574.997 us; speedup vs baseline: 3.5971x; 1.1560x over previous
//
#include <hip/hip_runtime.h>
#include <hip/hip_bf16.h>

#define NT_ 10000
#define B_  128
#define S_  500

typedef _Float16 h2_t __attribute__((ext_vector_type(2)));
typedef unsigned int uint32;

__device__ __forceinline__ uint32 pack2(float a, float b) {
    return __builtin_bit_cast(uint32, __builtin_amdgcn_cvt_pkrtz(a, b));
}
__device__ __forceinline__ float dot2(uint32 w, uint32 h, float acc) {
#if __has_builtin(__builtin_amdgcn_fdot2)
    return __builtin_amdgcn_fdot2(__builtin_bit_cast(h2_t, w),
                                  __builtin_bit_cast(h2_t, h), acc, false);
#else
    h2_t wv = __builtin_bit_cast(h2_t, w), hv = __builtin_bit_cast(h2_t, h);
    acc = fmaf((float)wv[0], (float)hv[0], acc);
    return fmaf((float)wv[1], (float)hv[1], acc);
#endif
}
__device__ __forceinline__ float rcpf(float x) {
    return __builtin_amdgcn_rcpf(x);
}
// quad_perm DPP add-reduce: x += x[lane^1]; x += x[lane^2]  (VALU pipe, no DS)
__device__ __forceinline__ float qstep(float x, const int ctrl) {
    int p;
    if (ctrl == 0xB1)
        p = __builtin_amdgcn_update_dpp(0, __builtin_bit_cast(int, x), 0xB1, 0xF, 0xF, true);
    else
        p = __builtin_amdgcn_update_dpp(0, __builtin_bit_cast(int, x), 0x4E, 0xF, 0xF, true);
    return x + __builtin_bit_cast(float, p);
}
#define QUAD_SUM(x) do { x = qstep(x, 0xB1); x = qstep(x, 0x4E); } while (0)

// ---------------------------------------------------------------------------
// Kernel A: per-topic precompute (blockIdx.y = 0: topicAct, 1: topicGate)
// ---------------------------------------------------------------------------
__global__ __launch_bounds__(128) void prep_topic(
    const float* __restrict__ emb_topic,
    const float* __restrict__ emb_resps,
    const float* __restrict__ W_in,
    const float* __restrict__ W_gate,
    float* __restrict__ topicAct,
    float* __restrict__ topicGate,
    float* __restrict__ respAct)
{
    const int u    = threadIdx.x;
    const int blk  = blockIdx.x;
    const int mode = blockIdx.y;
    __shared__ float e[8][128];

    if (blk == NT_ / 8) {
        if (mode) return;
        e[0][u] = emb_resps[u];
        e[1][u] = emb_resps[128 + u];
        __syncthreads();
        float a0 = 0.f, a1 = 0.f;
        for (int k = 0; k < 128; ++k) {
            float wv = W_in[(128 + k) * 128 + u];
            a0 += e[0][k] * wv;
            a1 += e[1][k] * wv;
        }
        respAct[u]       = a0;
        respAct[128 + u] = a1;
        return;
    }

    const int t0 = blk * 8;
    #pragma unroll
    for (int j = 0; j < 8; ++j) e[j][u] = emb_topic[(t0 + j) * 128 + u];
    __syncthreads();

    const float* __restrict__ W = mode ? (W_gate + 256 * 128) : W_in;
    float acc[8];
    #pragma unroll
    for (int j = 0; j < 8; ++j) acc[j] = 0.f;
    for (int k = 0; k < 128; ++k) {
        float wv = W[k * 128 + u];
        #pragma unroll
        for (int j = 0; j < 8; ++j) acc[j] += e[j][k] * wv;
    }
    float* __restrict__ dst = mode ? topicGate : topicAct;
    #pragma unroll
    for (int j = 0; j < 8; ++j) dst[(t0 + j) * 128 + u] = acc[j];
}

// ---------------------------------------------------------------------------
// Kernel B: per-(topic,resp) streams (blockIdx.y = mat 0..3)
//   streams[(t*2+r)*512 + m*128 + u]: m0: a@W_time[1:129]  m1: a@W_att[1:129]
//                                     m2: a@W_hint[1:129]  m3: a@W_gate[128:256]+topicGate
// ---------------------------------------------------------------------------
__global__ __launch_bounds__(128) void prep_streams(
    const float* __restrict__ topicAct,
    const float* __restrict__ topicGate,
    const float* __restrict__ respAct,
    const float* __restrict__ b_in,
    const float* __restrict__ W_time,
    const float* __restrict__ W_att,
    const float* __restrict__ W_hint,
    const float* __restrict__ W_gate,
    float* __restrict__ streams)
{
    const int u   = threadIdx.x;
    const int t0  = blockIdx.x * 8;
    const int mat = blockIdx.y;
    __shared__ float a_lds[16][128];

    const float bi = b_in[u];
    const float r0 = respAct[u];
    const float r1 = respAct[128 + u];
    #pragma unroll
    for (int j = 0; j < 8; ++j) {
        float ta = topicAct[(t0 + j) * 128 + u];
        a_lds[j * 2 + 0][u] = fmaxf(ta + r0 + bi, 0.f);
        a_lds[j * 2 + 1][u] = fmaxf(ta + r1 + bi, 0.f);
    }
    __syncthreads();

    const float* __restrict__ Wp =
        (mat == 0 ? W_time + 128 : mat == 1 ? W_att + 128 :
         mat == 2 ? W_hint + 128 : W_gate + 128 * 128) + u;

    float acc[16];
    #pragma unroll
    for (int r = 0; r < 16; ++r) acc[r] = 0.f;
    for (int k = 0; k < 128; ++k) {
        float wv = Wp[(size_t)k * 128];
        #pragma unroll
        for (int r = 0; r < 16; ++r) acc[r] += a_lds[r][k] * wv;
    }
    #pragma unroll
    for (int r = 0; r < 16; ++r) {
        float v = acc[r];
        int   t = t0 + (r >> 1);
        if (mat == 3) v += topicGate[t * 128 + u];
        streams[((size_t)t * 2 + (r & 1)) * 512 + mat * 128 + u] = v;
    }
}

// ---------------------------------------------------------------------------
// Kernel C: 500-step recurrence. 1 block/row, 512 thr = 128 u x 4 k-quads.
// R9 chain trims vs R8 (which measured 615us, VALUBusy 35%):
//  - output flush moved AFTER H-update (off the barrier->dot critical path)
//  - unified transcendental: q0 sigmoid / q1-3 tanh via one exp + one rcp
//    (was 5 exp + 5 IEEE divisions per lane); all div -> v_rcp_f32
//  - dot chains split x2 (10 accums depth 8, halves dot latency)
//  - sc 1-step register pipeline; sv 3-deep prefetch
// ---------------------------------------------------------------------------
#define LDS_BARRIER()                                         \
    do {                                                      \
        asm volatile("s_waitcnt lgkmcnt(0)" ::: "memory");    \
        __builtin_amdgcn_s_barrier();                         \
        asm volatile("" ::: "memory");                        \
    } while (0)

__global__ __launch_bounds__(512) __attribute__((amdgpu_waves_per_eu(2, 2)))
void recurrent(
    const int*   __restrict__ topics, const int* __restrict__ resps,
    const float* __restrict__ tf_, const float* __restrict__ af_,
    const float* __restrict__ hf_, const int* __restrict__ masks,
    const float* __restrict__ q_matrix, const float* __restrict__ init_h,
    const float* __restrict__ W_out,  const float* __restrict__ b_out,
    const float* __restrict__ W_time, const float* __restrict__ b_time,
    const float* __restrict__ W_att,  const float* __restrict__ b_att,
    const float* __restrict__ W_hint, const float* __restrict__ b_hint,
    const float* __restrict__ W_cap,  const float* __restrict__ b_cap,
    const float* __restrict__ w_lg,
    const float* __restrict__ W_gate, const float* __restrict__ b_gate,
    const float* __restrict__ streams,
    float* __restrict__ out)
{
    const int tid  = threadIdx.x;
    const int u    = tid >> 2;      // 0..127
    const int q    = tid & 3;       // k-quad / role
    const int lane = tid & 63;
    const int wv   = tid >> 6;      // wave 0..7
    const int b    = blockIdx.x;

    __shared__ int    sb_lds[S_];             // (topic*2+resp)*512
    __shared__ int    qb_lds[S_];             // topic*32
    __shared__ float4 sc_lds[S_];             // {tf, af, hf, capm(sign=mask)}
    __shared__ float  w_lds[2][32];
    __shared__ __align__(16) _Float16 ht16[2][176];  // quads at q*40 (bank-spread)
    __shared__ float  outbuf[8][2][128];      // [slot][which][u]

    const int base = b * S_;

    // ---- preload per-step data; fold cap+mask into sc.w ----
    {
        const float wcv0 = W_cap[0], wcv1 = W_cap[1], wcv2 = W_cap[2],
                    wcv3 = W_cap[3], wcv4 = W_cap[4], wcv5 = W_cap[5],
                    wcv6 = W_cap[6], wcv7 = W_cap[7], bcv = b_cap[0];
        for (int i = tid; i < S_; i += 512) {
            const int tpc = topics[base + i];
            const int rsp = resps [base + i];
            sb_lds[i] = (tpc * 2 + rsp) * 512;
            qb_lds[i] = tpc * 32;
            const float tf = tf_[base + i], af = af_[base + i], hf = hf_[base + i];
            const float capin = wcv0*tf + wcv1*af + wcv2*hf + wcv3*(tf*af)
                              + wcv4*(tf*hf) + wcv5*(af*hf) + wcv6*(tf*af*hf)
                              + wcv7 + bcv;
            const float cap = rcpf(1.f + __expf(-capin));
            sc_lds[i] = make_float4(tf, af, hf, masks[base + i] ? cap : -cap);
        }
    }

    // ---- f16-packed weights: ALL 5 mats for this lane's k-quad (80 u32) ----
    uint32 Wo[16], Wt[16], Wa[16], Wh[16], Wg[16];
    const int kb = q * 32;
    #pragma unroll
    for (int i = 0; i < 16; ++i) {
        const int k0 = kb + 2 * i, k1 = k0 + 1;
        Wo[i] = pack2(W_out [k0 * 128 + u],         W_out [k1 * 128 + u]);
        Wt[i] = pack2(W_time[(129 + k0) * 128 + u], W_time[(129 + k1) * 128 + u]);
        Wa[i] = pack2(W_att [(129 + k0) * 128 + u], W_att [(129 + k1) * 128 + u]);
        Wh[i] = pack2(W_hint[(129 + k0) * 128 + u], W_hint[(129 + k1) * 128 + u]);
        Wg[i] = pack2(W_gate[k0 * 128 + u],         W_gate[k1 * 128 + u]);
    }
    #pragma unroll
    for (int i = 0; i < 16; ++i) {
        asm volatile("" : "+v"(Wo[i]), "+v"(Wt[i]), "+v"(Wa[i]),
                          "+v"(Wh[i]), "+v"(Wg[i]));
    }

    // H[m][u] for m = q*8 .. q*8+7
    float H[8];
    #pragma unroll
    for (int j = 0; j < 8; ++j) H[j] = init_h[(q * 8 + j) * 128 + u];

    // per-lane role constants (q0: out/sigmoid, q1: time, q2: att, q3: hint)
    const float cst_b  = (q == 0 ? b_out : q == 1 ? b_time :
                          q == 2 ? b_att : b_hint)[u];
    const float cst_w0 = q == 1 ? W_time[u] : q == 2 ? W_att[u] :
                         q == 3 ? W_hint[u] : 0.f;
    const float wl_own = q == 1 ? w_lg[0] : q == 2 ? w_lg[1] :
                         q == 3 ? w_lg[2] : 0.f;
    const float bg = b_gate[u];
    const float aa = q == 0 ? 1.f : 2.f;    // sigmoid vs tanh exponent scale
    const float bb = q == 0 ? 1.f : 2.f;    // sigmoid vs tanh numerator
    // sv gather role: lane q gathers stream of mat q (time,att,hint,gate)
    const int   svofs = q * 128 + u;
    const float selt = (q == 0) ? 1.f : 0.f;
    const float sela = (q == 1) ? 1.f : 0.f;
    const float selh = (q == 2) ? 1.f : 0.f;
    const float selg = (q == 3) ? 1.f : 0.f;

    float* out_imp = out + B_ * (S_ - 1);

    __syncthreads();   // preload visible

    // ---- prime pipelines: sv 3-deep, qv 2-deep, sc 1-deep ----
    float sv_cur = streams[sb_lds[0] + svofs];
    float sv_n1  = streams[sb_lds[1] + svofs];
    float sv_n2  = streams[sb_lds[2] + svofs];
    float qv_cur = 0.f;
    if (tid < 32) {
        w_lds[0][tid] = q_matrix[qb_lds[0] + tid];
        qv_cur        = q_matrix[qb_lds[1] + tid];
    }
    __syncthreads();
    float4 wA = *(const float4*)&w_lds[0][q * 8];
    float4 wB = *(const float4*)&w_lds[0][q * 8 + 4];
    float4 sc_cur = sc_lds[0];

    #pragma unroll 1
    for (int s = 0; s < S_; ++s) {
        const int buf = s & 1;

        // per-step scalars from the register pipeline
        const float4 sc = sc_cur;
        const float tf = sc.x, af = sc.y, hf = sc.z;
        const float cap = fabsf(sc.w);
        const float msk = sc.w > 0.f ? 1.f : 0.f;

        // issue prefetches: sc for s+1, sv for s+3, qv for s+2
        sc_cur = sc_lds[(s + 1 < S_) ? s + 1 : S_ - 1];
        const int s3 = (s + 3 < S_) ? s + 3 : S_ - 1;
        const int s2 = (s + 2 < S_) ? s + 2 : S_ - 1;
        const float sv_new = streams[sb_lds[s3] + svofs];
        float qv_new = 0.f;
        if (tid < 32) qv_new = q_matrix[qb_lds[s2] + tid];

        // ---- h_tilde: 8-FMA partial + DPP quad reduce (VALU-only) ----
        float hp = wA.x * H[0] + wA.y * H[1] + wA.z * H[2] + wA.w * H[3]
                 + wB.x * H[4] + wB.y * H[5] + wB.z * H[6] + wB.w * H[7];
        QUAD_SUM(hp);
        if (q == 0) ht16[buf][(u >> 5) * 40 + (u & 31)] = (_Float16)hp;
        if (tid < 32) w_lds[buf ^ 1][tid] = qv_cur;    // w row for s+1
        LDS_BARRIER();

        const float4 wAn = *(const float4*)&w_lds[buf ^ 1][q * 8];
        const float4 wBn = *(const float4*)&w_lds[buf ^ 1][q * 8 + 4];

        // ---- 5 dots over OWN k-quad: 4 x ds_read_b128, split accumulators ----
        const _Float16* htq = &ht16[buf][q * 40];
        float zoA = 0, ztA = 0, zaA = 0, zhA = 0, zgA = 0;
        float zoB = 0, ztB = 0, zaB = 0, zhB = 0, zgB = 0;
        #pragma unroll
        for (int c = 0; c < 4; ++c) {
            const uint4 h4 = *(const uint4*)(htq + c * 8);
            zoA = dot2(Wo[c*4+0], h4.x, zoA); zoA = dot2(Wo[c*4+1], h4.y, zoA);
            zoB = dot2(Wo[c*4+2], h4.z, zoB); zoB = dot2(Wo[c*4+3], h4.w, zoB);
            ztA = dot2(Wt[c*4+0], h4.x, ztA); ztA = dot2(Wt[c*4+1], h4.y, ztA);
            ztB = dot2(Wt[c*4+2], h4.z, ztB); ztB = dot2(Wt[c*4+3], h4.w, ztB);
            zaA = dot2(Wa[c*4+0], h4.x, zaA); zaA = dot2(Wa[c*4+1], h4.y, zaA);
            zaB = dot2(Wa[c*4+2], h4.z, zaB); zaB = dot2(Wa[c*4+3], h4.w, zaB);
            zhA = dot2(Wh[c*4+0], h4.x, zhA); zhA = dot2(Wh[c*4+1], h4.y, zhA);
            zhB = dot2(Wh[c*4+2], h4.z, zhB); zhB = dot2(Wh[c*4+3], h4.w, zhB);
            zgA = dot2(Wg[c*4+0], h4.x, zgA); zgA = dot2(Wg[c*4+1], h4.y, zgA);
            zgB = dot2(Wg[c*4+2], h4.z, zgB); zgB = dot2(Wg[c*4+3], h4.w, zgB);
        }
        // combine + fold this lane's gathered stream value into its partial
        float zo = zoA + zoB;
        float zt = fmaf(selt, sv_cur, ztA + ztB);
        float za = fmaf(sela, sv_cur, zaA + zaB);
        float zh = fmaf(selh, sv_cur, zhA + zhB);
        float zg = fmaf(selg, sv_cur, zgA + zgB);
        QUAD_SUM(zo); QUAD_SUM(zt); QUAD_SUM(za); QUAD_SUM(zh); QUAD_SUM(zg);

        // ---- epilogue: unified sigmoid/tanh, one exp + one rcp per lane ----
        const float zsel = q == 0 ? zo : q == 1 ? zt : q == 2 ? za : zh;
        const float fac  = q == 1 ? tf : q == 2 ? af : q == 3 ? hf : 0.f;
        const float arg  = zsel + fac * cst_w0 + cst_b;
        const float e1   = __expf(aa * arg);
        const float val  = fmaf(-bb, rcpf(e1 + 1.f), 1.f); // q0: sigmoid, else tanh
        float gs = wl_own * fac * val;
        QUAD_SUM(gs);
        const float lg    = cap * fmaxf(gs, 0.f);
        const float gamma = rcpf(1.f + __expf(-(zg + bg)));

        const float gme = 1.f + msk * (gamma - 1.f);
        const float lge = msk * lg;
        H[0] = fmaf(gme, H[0], wA.x * lge); H[1] = fmaf(gme, H[1], wA.y * lge);
        H[2] = fmaf(gme, H[2], wA.z * lge); H[3] = fmaf(gme, H[3], wA.w * lge);
        H[4] = fmaf(gme, H[4], wB.x * lge); H[5] = fmaf(gme, H[5], wB.y * lge);
        H[6] = fmaf(gme, H[6], wB.z * lge); H[7] = fmaf(gme, H[7], wB.w * lge);

        if (q == 0) {
            outbuf[s & 7][0][u] = msk * val;   // val = sigmoid(z_out+bo) on q0
            outbuf[s & 7][1][u] = lge;
        }

        // ---- deferred output flush (moved OFF the critical path) ----
        if ((s & 3) == 0 && s) {
            const int st = (s - 4) + (wv >> 1);
            const int which = wv & 1;
            const float2 p = *(const float2*)&outbuf[st & 7][which][2 * lane];
            float v = p.x + p.y;
            #pragma unroll
            for (int o = 1; o < 64; o <<= 1) v += __shfl_xor(v, o);
            if (lane == 0) {
                v *= (1.f / 128.f);
                if (which == 0) { if (st >= 1) out[b * (S_ - 1) + st - 1] = v; }
                else            out_imp[b * S_ + st] = v;
            }
        }

        // rotate pipelines
        wA = wAn; wB = wBn;
        sv_cur = sv_n1; sv_n1 = sv_n2; sv_n2 = sv_new; qv_cur = qv_new;
    }

    // ---- final flush: steps 496..499 ----
    __syncthreads();
    {
        const int st = 496 + (wv >> 1);
        const int which = wv & 1;
        const float2 p = *(const float2*)&outbuf[st & 7][which][2 * lane];
        float v = p.x + p.y;
        #pragma unroll
        for (int o = 1; o < 64; o <<= 1) v += __shfl_xor(v, o);
        if (lane == 0) {
            v *= (1.f / 128.f);
            if (which == 0) out[b * (S_ - 1) + st - 1] = v;
            else            out_imp[b * S_ + st] = v;
        }
    }
}

// ---------------------------------------------------------------------------
extern "C" void kernel_launch(void* const* d_in, const int* in_sizes, int n_in,
                              void* d_out, int out_size, void* d_ws, size_t ws_size,
                              hipStream_t stream)
{
    (void)in_sizes; (void)n_in; (void)out_size; (void)ws_size;

    const int*   topics    = (const int*)  d_in[0];
    const int*   resps     = (const int*)  d_in[1];
    const float* tf        = (const float*)d_in[2];
    const float* af        = (const float*)d_in[3];
    const float* hf        = (const float*)d_in[4];
    const int*   masks     = (const int*)  d_in[5];
    /* d_in[6] = training (ignored) */
    const float* emb_topic = (const float*)d_in[7];
    const float* emb_resps = (const float*)d_in[8];
    const float* q_matrix  = (const float*)d_in[9];
    const float* W_in      = (const float*)d_in[10];
    const float* b_in      = (const float*)d_in[11];
    const float* init_h    = (const float*)d_in[12];
    const float* W_out     = (const float*)d_in[13];
    const float* b_out     = (const float*)d_in[14];
    const float* W_time    = (const float*)d_in[15];
    const float* b_time    = (const float*)d_in[16];
    const float* W_att     = (const float*)d_in[17];
    const float* b_att     = (const float*)d_in[18];
    const float* W_hint    = (const float*)d_in[19];
    const float* b_hint    = (const float*)d_in[20];
    const float* W_cap     = (const float*)d_in[21];
    const float* b_cap     = (const float*)d_in[22];
    const float* w_lg      = (const float*)d_in[23];
    const float* W_gate    = (const float*)d_in[24];
    const float* b_gate    = (const float*)d_in[25];

    float* ws        = (float*)d_ws;
    float* topicAct  = ws;                         // 10000*128
    float* topicGate = topicAct + NT_ * 128;       // 10000*128
    float* respAct   = topicGate + NT_ * 128;      // 256
    float* streams   = respAct + 256;              // 10000*2*512

    prep_topic  <<<dim3(NT_ / 8 + 1, 2), 128, 0, stream>>>(
        emb_topic, emb_resps, W_in, W_gate, topicAct, topicGate, respAct);
    prep_streams<<<dim3(NT_ / 8, 4),     128, 0, stream>>>(
        topicAct, topicGate, respAct, b_in,
        W_time, W_att, W_hint, W_gate, streams);
    recurrent   <<<B_, 512, 0, stream>>>(topics, resps, tf, af, hf, masks,
                                         q_matrix, init_h,
                                         W_out, b_out, W_time, b_time,
                                         W_att, b_att, W_hint, b_hint,
                                         W_cap, b_cap, w_lg, W_gate, b_gate,
                                         streams, (float*)d_out);
}

// Round 10
// 499.184 us; speedup vs baseline: 4.1435x; 1.1519x over previous
//
#include <hip/hip_runtime.h>
#include <hip/hip_bf16.h>

#define NT_ 10000
#define B_  128
#define S_  500

typedef _Float16 h2_t __attribute__((ext_vector_type(2)));
typedef unsigned int uint32;

__device__ __forceinline__ uint32 pack2(float a, float b) {
    return __builtin_bit_cast(uint32, __builtin_amdgcn_cvt_pkrtz(a, b));
}
__device__ __forceinline__ float dot2(uint32 w, uint32 h, float acc) {
#if __has_builtin(__builtin_amdgcn_fdot2)
    return __builtin_amdgcn_fdot2(__builtin_bit_cast(h2_t, w),
                                  __builtin_bit_cast(h2_t, h), acc, false);
#else
    h2_t wv = __builtin_bit_cast(h2_t, w), hv = __builtin_bit_cast(h2_t, h);
    acc = fmaf((float)wv[0], (float)hv[0], acc);
    return fmaf((float)wv[1], (float)hv[1], acc);
#endif
}
__device__ __forceinline__ float rcpf(float x) {
    return __builtin_amdgcn_rcpf(x);
}
// quad_perm DPP add-reduce: x += x[lane^1]; x += x[lane^2]  (VALU pipe, no DS)
__device__ __forceinline__ float qstep(float x, const int ctrl) {
    int p;
    if (ctrl == 0xB1)
        p = __builtin_amdgcn_update_dpp(0, __builtin_bit_cast(int, x), 0xB1, 0xF, 0xF, true);
    else
        p = __builtin_amdgcn_update_dpp(0, __builtin_bit_cast(int, x), 0x4E, 0xF, 0xF, true);
    return x + __builtin_bit_cast(float, p);
}
#define QUAD_SUM(x) do { x = qstep(x, 0xB1); x = qstep(x, 0x4E); } while (0)

// ---------------------------------------------------------------------------
// Kernel A: per-topic precompute (blockIdx.y = 0: topicAct, 1: topicGate)
// ---------------------------------------------------------------------------
__global__ __launch_bounds__(128) void prep_topic(
    const float* __restrict__ emb_topic,
    const float* __restrict__ emb_resps,
    const float* __restrict__ W_in,
    const float* __restrict__ W_gate,
    float* __restrict__ topicAct,
    float* __restrict__ topicGate,
    float* __restrict__ respAct)
{
    const int u    = threadIdx.x;
    const int blk  = blockIdx.x;
    const int mode = blockIdx.y;
    __shared__ float e[8][128];

    if (blk == NT_ / 8) {
        if (mode) return;
        e[0][u] = emb_resps[u];
        e[1][u] = emb_resps[128 + u];
        __syncthreads();
        float a0 = 0.f, a1 = 0.f;
        for (int k = 0; k < 128; ++k) {
            float wv = W_in[(128 + k) * 128 + u];
            a0 += e[0][k] * wv;
            a1 += e[1][k] * wv;
        }
        respAct[u]       = a0;
        respAct[128 + u] = a1;
        return;
    }

    const int t0 = blk * 8;
    #pragma unroll
    for (int j = 0; j < 8; ++j) e[j][u] = emb_topic[(t0 + j) * 128 + u];
    __syncthreads();

    const float* __restrict__ W = mode ? (W_gate + 256 * 128) : W_in;
    float acc[8];
    #pragma unroll
    for (int j = 0; j < 8; ++j) acc[j] = 0.f;
    for (int k = 0; k < 128; ++k) {
        float wv = W[k * 128 + u];
        #pragma unroll
        for (int j = 0; j < 8; ++j) acc[j] += e[j][k] * wv;
    }
    float* __restrict__ dst = mode ? topicGate : topicAct;
    #pragma unroll
    for (int j = 0; j < 8; ++j) dst[(t0 + j) * 128 + u] = acc[j];
}

// ---------------------------------------------------------------------------
// Kernel B: per-(topic,resp) streams (blockIdx.y = mat 0..3)
// ---------------------------------------------------------------------------
__global__ __launch_bounds__(128) void prep_streams(
    const float* __restrict__ topicAct,
    const float* __restrict__ topicGate,
    const float* __restrict__ respAct,
    const float* __restrict__ b_in,
    const float* __restrict__ W_time,
    const float* __restrict__ W_att,
    const float* __restrict__ W_hint,
    const float* __restrict__ W_gate,
    float* __restrict__ streams)
{
    const int u   = threadIdx.x;
    const int t0  = blockIdx.x * 8;
    const int mat = blockIdx.y;
    __shared__ float a_lds[16][128];

    const float bi = b_in[u];
    const float r0 = respAct[u];
    const float r1 = respAct[128 + u];
    #pragma unroll
    for (int j = 0; j < 8; ++j) {
        float ta = topicAct[(t0 + j) * 128 + u];
        a_lds[j * 2 + 0][u] = fmaxf(ta + r0 + bi, 0.f);
        a_lds[j * 2 + 1][u] = fmaxf(ta + r1 + bi, 0.f);
    }
    __syncthreads();

    const float* __restrict__ Wp =
        (mat == 0 ? W_time + 128 : mat == 1 ? W_att + 128 :
         mat == 2 ? W_hint + 128 : W_gate + 128 * 128) + u;

    float acc[16];
    #pragma unroll
    for (int r = 0; r < 16; ++r) acc[r] = 0.f;
    for (int k = 0; k < 128; ++k) {
        float wv = Wp[(size_t)k * 128];
        #pragma unroll
        for (int r = 0; r < 16; ++r) acc[r] += a_lds[r][k] * wv;
    }
    #pragma unroll
    for (int r = 0; r < 16; ++r) {
        float v = acc[r];
        int   t = t0 + (r >> 1);
        if (mat == 3) v += topicGate[t * 128 + u];
        streams[((size_t)t * 2 + (r & 1)) * 512 + mat * 128 + u] = v;
    }
}

// ---------------------------------------------------------------------------
// Kernel C: 500-step recurrence. 1 block/row, 512 thr = 128 u x 4 k-quads.
// R10 vs R9 (520us, VALUBusy 32%): the R9 "3-deep" sv prefetch was fake -
// #pragma unroll 1 register rotation forced s_waitcnt vmcnt in the SAME
// iteration the load was issued (~1 body of distance < L3 latency). Explicit
// 4x unroll with period-4 named registers (sv0..3, qq0..3) makes rotation
// pure renaming: each load's waitcnt lands 4 bodies (~2000cyc) later.
// ---------------------------------------------------------------------------
#define LDS_BARRIER()                                         \
    do {                                                      \
        asm volatile("s_waitcnt lgkmcnt(0)" ::: "memory");    \
        __builtin_amdgcn_s_barrier();                         \
        asm volatile("" ::: "memory");                        \
    } while (0)

__global__ __launch_bounds__(512) __attribute__((amdgpu_waves_per_eu(2, 2)))
void recurrent(
    const int*   __restrict__ topics, const int* __restrict__ resps,
    const float* __restrict__ tf_, const float* __restrict__ af_,
    const float* __restrict__ hf_, const int* __restrict__ masks,
    const float* __restrict__ q_matrix, const float* __restrict__ init_h,
    const float* __restrict__ W_out,  const float* __restrict__ b_out,
    const float* __restrict__ W_time, const float* __restrict__ b_time,
    const float* __restrict__ W_att,  const float* __restrict__ b_att,
    const float* __restrict__ W_hint, const float* __restrict__ b_hint,
    const float* __restrict__ W_cap,  const float* __restrict__ b_cap,
    const float* __restrict__ w_lg,
    const float* __restrict__ W_gate, const float* __restrict__ b_gate,
    const float* __restrict__ streams,
    float* __restrict__ out)
{
    const int tid  = threadIdx.x;
    const int u    = tid >> 2;      // 0..127
    const int q    = tid & 3;       // k-quad / role
    const int lane = tid & 63;
    const int wv   = tid >> 6;      // wave 0..7
    const int b    = blockIdx.x;

    __shared__ int    sb_lds[S_];             // (topic*2+resp)*512
    __shared__ int    qb_lds[S_];             // topic*32
    __shared__ float4 sc_lds[S_];             // {tf, af, hf, capm(sign=mask)}
    __shared__ float  w_lds[2][32];
    __shared__ __align__(16) _Float16 ht16[2][176];  // quads at q*40 (bank-spread)
    __shared__ float  outbuf[8][2][128];      // [slot][which][u]

    const int base = b * S_;

    // ---- preload per-step data; fold cap+mask into sc.w ----
    {
        const float wcv0 = W_cap[0], wcv1 = W_cap[1], wcv2 = W_cap[2],
                    wcv3 = W_cap[3], wcv4 = W_cap[4], wcv5 = W_cap[5],
                    wcv6 = W_cap[6], wcv7 = W_cap[7], bcv = b_cap[0];
        for (int i = tid; i < S_; i += 512) {
            const int tpc = topics[base + i];
            const int rsp = resps [base + i];
            sb_lds[i] = (tpc * 2 + rsp) * 512;
            qb_lds[i] = tpc * 32;
            const float tf = tf_[base + i], af = af_[base + i], hf = hf_[base + i];
            const float capin = wcv0*tf + wcv1*af + wcv2*hf + wcv3*(tf*af)
                              + wcv4*(tf*hf) + wcv5*(af*hf) + wcv6*(tf*af*hf)
                              + wcv7 + bcv;
            const float cap = rcpf(1.f + __expf(-capin));
            sc_lds[i] = make_float4(tf, af, hf, masks[base + i] ? cap : -cap);
        }
    }

    // ---- f16-packed weights: ALL 5 mats for this lane's k-quad (80 u32) ----
    uint32 Wo[16], Wt[16], Wa[16], Wh[16], Wg[16];
    const int kb = q * 32;
    #pragma unroll
    for (int i = 0; i < 16; ++i) {
        const int k0 = kb + 2 * i, k1 = k0 + 1;
        Wo[i] = pack2(W_out [k0 * 128 + u],         W_out [k1 * 128 + u]);
        Wt[i] = pack2(W_time[(129 + k0) * 128 + u], W_time[(129 + k1) * 128 + u]);
        Wa[i] = pack2(W_att [(129 + k0) * 128 + u], W_att [(129 + k1) * 128 + u]);
        Wh[i] = pack2(W_hint[(129 + k0) * 128 + u], W_hint[(129 + k1) * 128 + u]);
        Wg[i] = pack2(W_gate[k0 * 128 + u],         W_gate[k1 * 128 + u]);
    }
    #pragma unroll
    for (int i = 0; i < 16; ++i) {
        asm volatile("" : "+v"(Wo[i]), "+v"(Wt[i]), "+v"(Wa[i]),
                          "+v"(Wh[i]), "+v"(Wg[i]));
    }

    // H[m][u] for m = q*8 .. q*8+7
    float H[8];
    #pragma unroll
    for (int j = 0; j < 8; ++j) H[j] = init_h[(q * 8 + j) * 128 + u];

    // per-lane role constants (q0: out/sigmoid, q1: time, q2: att, q3: hint)
    const float cst_b  = (q == 0 ? b_out : q == 1 ? b_time :
                          q == 2 ? b_att : b_hint)[u];
    const float cst_w0 = q == 1 ? W_time[u] : q == 2 ? W_att[u] :
                         q == 3 ? W_hint[u] : 0.f;
    const float wl_own = q == 1 ? w_lg[0] : q == 2 ? w_lg[1] :
                         q == 3 ? w_lg[2] : 0.f;
    const float bg = b_gate[u];
    const float aa = q == 0 ? 1.f : 2.f;    // sigmoid vs tanh exponent scale
    const float bb = q == 0 ? 1.f : 2.f;    // sigmoid vs tanh numerator
    // sv gather role: lane q gathers stream of mat q (time,att,hint,gate)
    const int   svofs = q * 128 + u;
    const float selt = (q == 0) ? 1.f : 0.f;
    const float sela = (q == 1) ? 1.f : 0.f;
    const float selh = (q == 2) ? 1.f : 0.f;
    const float selg = (q == 3) ? 1.f : 0.f;

    float* out_imp = out + B_ * (S_ - 1);

    __syncthreads();   // preload visible

    // ---- prime: sv j = stream val for step j; qq j = q row for step j+1 ----
    float sv0 = streams[sb_lds[0] + svofs];
    float sv1 = streams[sb_lds[1] + svofs];
    float sv2 = streams[sb_lds[2] + svofs];
    float sv3 = streams[sb_lds[3] + svofs];
    float qq0 = 0.f, qq1 = 0.f, qq2 = 0.f, qq3 = 0.f;
    if (tid < 32) {
        w_lds[0][tid] = q_matrix[qb_lds[0] + tid];
        qq0 = q_matrix[qb_lds[1] + tid];
        qq1 = q_matrix[qb_lds[2] + tid];
        qq2 = q_matrix[qb_lds[3] + tid];
        qq3 = q_matrix[qb_lds[4] + tid];
    }
    __syncthreads();
    float4 wA = *(const float4*)&w_lds[0][q * 8];
    float4 wB = *(const float4*)&w_lds[0][q * 8 + 4];

// One step body. J = compile-time phase (0..3); SV holds this step's stream
// value and is reloaded for step s+4 (consumed at the same phase next iter);
// QQ holds the q_matrix row for step s+1 and is reloaded for step s+5.
#define STEP(J, SV, QQ)                                                        \
    {                                                                          \
        const int s = s4 + (J);                                                \
        const float4 sc = sc_lds[s];                                           \
        const float tf = sc.x, af = sc.y, hf = sc.z;                           \
        const float cap = fabsf(sc.w);                                         \
        const float msk = sc.w > 0.f ? 1.f : 0.f;                              \
        /* h_tilde partial + DPP quad reduce */                                \
        float hp = wA.x * H[0] + wA.y * H[1] + wA.z * H[2] + wA.w * H[3]       \
                 + wB.x * H[4] + wB.y * H[5] + wB.z * H[6] + wB.w * H[7];      \
        QUAD_SUM(hp);                                                          \
        if (q == 0) ht16[(J) & 1][(u >> 5) * 40 + (u & 31)] = (_Float16)hp;    \
        if (tid < 32) {                                                        \
            w_lds[((J) & 1) ^ 1][tid] = QQ;                                    \
            const int sp5 = (s + 5 < S_) ? s + 5 : S_ - 1;                     \
            QQ = q_matrix[qb_lds[sp5] + tid];  /* row for s+5, used J next */  \
        }                                                                      \
        LDS_BARRIER();                                                         \
        const float4 wAn = *(const float4*)&w_lds[((J) & 1) ^ 1][q * 8];       \
        const float4 wBn = *(const float4*)&w_lds[((J) & 1) ^ 1][q * 8 + 4];   \
        /* 5 dots over own k-quad */                                           \
        const _Float16* htq = &ht16[(J) & 1][q * 40];                          \
        float zoA = 0, ztA = 0, zaA = 0, zhA = 0, zgA = 0;                     \
        float zoB = 0, ztB = 0, zaB = 0, zhB = 0, zgB = 0;                     \
        _Pragma("unroll")                                                      \
        for (int c = 0; c < 4; ++c) {                                          \
            const uint4 h4 = *(const uint4*)(htq + c * 8);                     \
            zoA = dot2(Wo[c*4+0], h4.x, zoA); zoA = dot2(Wo[c*4+1], h4.y, zoA);\
            zoB = dot2(Wo[c*4+2], h4.z, zoB); zoB = dot2(Wo[c*4+3], h4.w, zoB);\
            ztA = dot2(Wt[c*4+0], h4.x, ztA); ztA = dot2(Wt[c*4+1], h4.y, ztA);\
            ztB = dot2(Wt[c*4+2], h4.z, ztB); ztB = dot2(Wt[c*4+3], h4.w, ztB);\
            zaA = dot2(Wa[c*4+0], h4.x, zaA); zaA = dot2(Wa[c*4+1], h4.y, zaA);\
            zaB = dot2(Wa[c*4+2], h4.z, zaB); zaB = dot2(Wa[c*4+3], h4.w, zaB);\
            zhA = dot2(Wh[c*4+0], h4.x, zhA); zhA = dot2(Wh[c*4+1], h4.y, zhA);\
            zhB = dot2(Wh[c*4+2], h4.z, zhB); zhB = dot2(Wh[c*4+3], h4.w, zhB);\
            zgA = dot2(Wg[c*4+0], h4.x, zgA); zgA = dot2(Wg[c*4+1], h4.y, zgA);\
            zgB = dot2(Wg[c*4+2], h4.z, zgB); zgB = dot2(Wg[c*4+3], h4.w, zgB);\
        }                                                                      \
        float zo = zoA + zoB;                                                  \
        float zt = fmaf(selt, SV, ztA + ztB);                                  \
        float za = fmaf(sela, SV, zaA + zaB);                                  \
        float zh = fmaf(selh, SV, zhA + zhB);                                  \
        float zg = fmaf(selg, SV, zgA + zgB);                                  \
        {                                                                      \
            const int sp4 = (s + 4 < S_) ? s + 4 : S_ - 1;                     \
            SV = streams[sb_lds[sp4] + svofs];  /* for s+4, same phase next */ \
        }                                                                      \
        QUAD_SUM(zo); QUAD_SUM(zt); QUAD_SUM(za); QUAD_SUM(zh); QUAD_SUM(zg);  \
        /* epilogue: unified sigmoid/tanh */                                   \
        const float zsel = q == 0 ? zo : q == 1 ? zt : q == 2 ? za : zh;       \
        const float fac  = q == 1 ? tf : q == 2 ? af : q == 3 ? hf : 0.f;      \
        const float arg  = zsel + fac * cst_w0 + cst_b;                        \
        const float e1   = __expf(aa * arg);                                   \
        const float val  = fmaf(-bb, rcpf(e1 + 1.f), 1.f);                     \
        float gs = wl_own * fac * val;                                         \
        QUAD_SUM(gs);                                                          \
        const float lg    = cap * fmaxf(gs, 0.f);                              \
        const float gamma = rcpf(1.f + __expf(-(zg + bg)));                    \
        const float gme = 1.f + msk * (gamma - 1.f);                           \
        const float lge = msk * lg;                                            \
        H[0] = fmaf(gme, H[0], wA.x * lge); H[1] = fmaf(gme, H[1], wA.y * lge);\
        H[2] = fmaf(gme, H[2], wA.z * lge); H[3] = fmaf(gme, H[3], wA.w * lge);\
        H[4] = fmaf(gme, H[4], wB.x * lge); H[5] = fmaf(gme, H[5], wB.y * lge);\
        H[6] = fmaf(gme, H[6], wB.z * lge); H[7] = fmaf(gme, H[7], wB.w * lge);\
        if (q == 0) {                                                          \
            outbuf[s & 7][0][u] = msk * val;                                   \
            outbuf[s & 7][1][u] = lge;                                         \
        }                                                                      \
        if ((J) == 0 && s4 > 0) {  /* flush steps s4-4..s4-1 */                \
            const int st = (s4 - 4) + (wv >> 1);                               \
            const int which = wv & 1;                                          \
            const float2 p = *(const float2*)&outbuf[st & 7][which][2 * lane]; \
            float v = p.x + p.y;                                               \
            _Pragma("unroll")                                                  \
            for (int o = 1; o < 64; o <<= 1) v += __shfl_xor(v, o);            \
            if (lane == 0) {                                                   \
                v *= (1.f / 128.f);                                            \
                if (which == 0) { if (st >= 1) out[b * (S_ - 1) + st - 1] = v; } \
                else            out_imp[b * S_ + st] = v;                      \
            }                                                                  \
        }                                                                      \
        wA = wAn; wB = wBn;                                                    \
    }

    #pragma unroll 1
    for (int s4 = 0; s4 < S_; s4 += 4) {
        STEP(0, sv0, qq0)
        STEP(1, sv1, qq1)
        STEP(2, sv2, qq2)
        STEP(3, sv3, qq3)
    }
#undef STEP

    // ---- final flush: steps 496..499 ----
    __syncthreads();
    {
        const int st = 496 + (wv >> 1);
        const int which = wv & 1;
        const float2 p = *(const float2*)&outbuf[st & 7][which][2 * lane];
        float v = p.x + p.y;
        #pragma unroll
        for (int o = 1; o < 64; o <<= 1) v += __shfl_xor(v, o);
        if (lane == 0) {
            v *= (1.f / 128.f);
            if (which == 0) out[b * (S_ - 1) + st - 1] = v;
            else            out_imp[b * S_ + st] = v;
        }
    }
}

// ---------------------------------------------------------------------------
extern "C" void kernel_launch(void* const* d_in, const int* in_sizes, int n_in,
                              void* d_out, int out_size, void* d_ws, size_t ws_size,
                              hipStream_t stream)
{
    (void)in_sizes; (void)n_in; (void)out_size; (void)ws_size;

    const int*   topics    = (const int*)  d_in[0];
    const int*   resps     = (const int*)  d_in[1];
    const float* tf        = (const float*)d_in[2];
    const float* af        = (const float*)d_in[3];
    const float* hf        = (const float*)d_in[4];
    const int*   masks     = (const int*)  d_in[5];
    /* d_in[6] = training (ignored) */
    const float* emb_topic = (const float*)d_in[7];
    const float* emb_resps = (const float*)d_in[8];
    const float* q_matrix  = (const float*)d_in[9];
    const float* W_in      = (const float*)d_in[10];
    const float* b_in      = (const float*)d_in[11];
    const float* init_h    = (const float*)d_in[12];
    const float* W_out     = (const float*)d_in[13];
    const float* b_out     = (const float*)d_in[14];
    const float* W_time    = (const float*)d_in[15];
    const float* b_time    = (const float*)d_in[16];
    const float* W_att     = (const float*)d_in[17];
    const float* b_att     = (const float*)d_in[18];
    const float* W_hint    = (const float*)d_in[19];
    const float* b_hint    = (const float*)d_in[20];
    const float* W_cap     = (const float*)d_in[21];
    const float* b_cap     = (const float*)d_in[22];
    const float* w_lg      = (const float*)d_in[23];
    const float* W_gate    = (const float*)d_in[24];
    const float* b_gate    = (const float*)d_in[25];

    float* ws        = (float*)d_ws;
    float* topicAct  = ws;                         // 10000*128
    float* topicGate = topicAct + NT_ * 128;       // 10000*128
    float* respAct   = topicGate + NT_ * 128;      // 256
    float* streams   = respAct + 256;              // 10000*2*512

    prep_topic  <<<dim3(NT_ / 8 + 1, 2), 128, 0, stream>>>(
        emb_topic, emb_resps, W_in, W_gate, topicAct, topicGate, respAct);
    prep_streams<<<dim3(NT_ / 8, 4),     128, 0, stream>>>(
        topicAct, topicGate, respAct, b_in,
        W_time, W_att, W_hint, W_gate, streams);
    recurrent   <<<B_, 512, 0, stream>>>(topics, resps, tf, af, hf, masks,
                                         q_matrix, init_h,
                                         W_out, b_out, W_time, b_time,
                                         W_att, b_att, W_hint, b_hint,
                                         W_cap, b_cap, w_lg, W_gate, b_gate,
                                         streams, (float*)d_out);
}